// Round 3
// baseline (633.369 us; speedup 1.0000x reference)
//
#include <hip/hip_runtime.h>
#include <cmath>

#define WS 11
#define TILE 32
#define PADW 44                    // vv row stride (floats), 16B-aligned
#define IMH 512
#define IMW 512
#define OH 502
#define OW 502
#define NPLANES 96                 // 32 * 3
#define GX 16
#define GY 16
#define NBLK (GX * GY * NPLANES)   // 24576
#define NOUT ((long long)NPLANES * OH * OW)  // 24192384

struct GaussW { float g[WS]; };

// ---------------- kernel 1: range-detection flags over img1 ----------------
__global__ __launch_bounds__(256) void flags_kernel(const float* __restrict__ img1,
                                                    unsigned* __restrict__ flags,
                                                    int n4) {
    int idx = blockIdx.x * blockDim.x + threadIdx.x;
    int stride = gridDim.x * blockDim.x;
    int gt = 0, lt = 0;
    const float4* p = reinterpret_cast<const float4*>(img1);
    for (int i = idx; i < n4; i += stride) {
        float4 v = p[i];
        gt |= (v.x > 128.f) | (v.y > 128.f) | (v.z > 128.f) | (v.w > 128.f);
        lt |= (v.x < -0.5f) | (v.y < -0.5f) | (v.z < -0.5f) | (v.w < -0.5f);
    }
    if (gt) atomicOr(&flags[0], 1u);
    if (lt) atomicOr(&flags[1], 1u);
}

// ---------------- kernel 2: tiled separable SSIM ----------------
// Vertical pass reads global directly (L1-resident working set, ~14 KB/block).
// Only the 5 vertical-convolved planes live in LDS (28.2 KB -> 5 blocks/CU).
__global__ __launch_bounds__(256, 5) void ssim_kernel(const float* __restrict__ img1,
                                                      const float* __restrict__ img2,
                                                      const unsigned* __restrict__ flags,
                                                      double* __restrict__ sum_out,
                                                      double* __restrict__ partials,
                                                      int use_partials,
                                                      GaussW gw) {
    __shared__ float vv[5][TILE][PADW];     // 5 x 32 x 44 floats = 28160 B
    __shared__ float wsum[4];

    const int plane = blockIdx.z;
    const int tx0 = blockIdx.x * TILE;   // output col origin
    const int ty0 = blockIdx.y * TILE;   // output row origin
    const float* p1 = img1 + (size_t)plane * (IMH * IMW);
    const float* p2 = img2 + (size_t)plane * (IMH * IMW);
    const int tid = threadIdx.x;

    // ---- vertical Gaussian pass: 32 rows x 11 float4 col-groups ----
    for (int i = tid; i < TILE * 11; i += 256) {
        int r = i / 11, cg = i - r * 11;
        int gr = ty0 + r;                // vertical window starts at this image row
        int gc = tx0 + cg * 4;
        bool vec = (gc + 3 < IMW);       // edge col-groups (only at tx0=480, cg>=8)

        float m1[4] = {0,0,0,0}, m2[4] = {0,0,0,0};
        float q1[4] = {0,0,0,0}, q2[4] = {0,0,0,0}, q12[4] = {0,0,0,0};
        #pragma unroll
        for (int k = 0; k < WS; ++k) {
            int row = gr + k; row = row < IMH - 1 ? row : IMH - 1;  // clamp (values unused for masked outputs)
            const float* r1 = p1 + (size_t)row * IMW;
            const float* r2 = p2 + (size_t)row * IMW;
            float a[4], b[4];
            if (vec) {
                float4 a4 = *reinterpret_cast<const float4*>(r1 + gc);
                float4 b4 = *reinterpret_cast<const float4*>(r2 + gc);
                a[0]=a4.x; a[1]=a4.y; a[2]=a4.z; a[3]=a4.w;
                b[0]=b4.x; b[1]=b4.y; b[2]=b4.z; b[3]=b4.w;
            } else {
                #pragma unroll
                for (int j = 0; j < 4; ++j) {
                    int c = gc + j; c = c < IMW - 1 ? c : IMW - 1;  // clamp, value unused
                    a[j] = r1[c]; b[j] = r2[c];
                }
            }
            float w = gw.g[k];
            #pragma unroll
            for (int j = 0; j < 4; ++j) {
                m1[j]  += w * a[j];
                m2[j]  += w * b[j];
                q1[j]  += w * (a[j] * a[j]);
                q2[j]  += w * (b[j] * b[j]);
                q12[j] += w * (a[j] * b[j]);
            }
        }
        *reinterpret_cast<float4*>(&vv[0][r][cg * 4]) = make_float4(m1[0], m1[1], m1[2], m1[3]);
        *reinterpret_cast<float4*>(&vv[1][r][cg * 4]) = make_float4(m2[0], m2[1], m2[2], m2[3]);
        *reinterpret_cast<float4*>(&vv[2][r][cg * 4]) = make_float4(q1[0], q1[1], q1[2], q1[3]);
        *reinterpret_cast<float4*>(&vv[3][r][cg * 4]) = make_float4(q2[0], q2[1], q2[2], q2[3]);
        *reinterpret_cast<float4*>(&vv[4][r][cg * 4]) = make_float4(q12[0], q12[1], q12[2], q12[3]);
    }
    __syncthreads();

    // ---- constants from range flags ----
    float maxv = flags[0] ? 255.f : 1.f;
    float minv = flags[1] ? -1.f : 0.f;
    float L = maxv - minv;
    float C1 = (0.01f * L) * (0.01f * L);
    float C2 = (0.03f * L) * (0.03f * L);

    // ---- horizontal pass: 256 threads, 4 outputs each, per-quantity windows ----
    float local = 0.f;
    {
        const int r = tid >> 3;          // 0..31
        const int cg = tid & 7;          // 0..7 -> output cols cg*4 .. cg*4+3
        float mu1[4], mu2[4], x2[4], y2[4], xy[4];
        #pragma unroll
        for (int q = 0; q < 5; ++q) {
            float w[16];
            #pragma unroll
            for (int t = 0; t < 4; ++t) {
                float4 v = *reinterpret_cast<const float4*>(&vv[q][r][cg * 4 + t * 4]);
                w[t*4+0] = v.x; w[t*4+1] = v.y; w[t*4+2] = v.z; w[t*4+3] = v.w;
            }
            float* acc = (q == 0) ? mu1 : (q == 1) ? mu2 : (q == 2) ? x2 : (q == 3) ? y2 : xy;
            #pragma unroll
            for (int j = 0; j < 4; ++j) {
                float s = 0.f;
                #pragma unroll
                for (int k = 0; k < WS; ++k) s += gw.g[k] * w[j + k];
                acc[j] = s;
            }
        }
        const int oy = ty0 + r;
        #pragma unroll
        for (int j = 0; j < 4; ++j) {
            int ox = tx0 + cg * 4 + j;
            if (oy < OH && ox < OW) {
                float mu1s = mu1[j] * mu1[j], mu2s = mu2[j] * mu2[j], mu12 = mu1[j] * mu2[j];
                float sg1 = x2[j] - mu1s, sg2 = y2[j] - mu2s, sg12 = xy[j] - mu12;
                float v1 = 2.f * sg12 + C2;
                float v2 = sg1 + sg2 + C2;
                float num = (2.f * mu12 + C1) * v1;
                float den = (mu1s + mu2s + C1) * v2;
                float rc = __builtin_amdgcn_rcpf(den);
                rc = rc * (2.0f - den * rc);   // 1 Newton step
                local += num * rc;
            }
        }
    }

    // ---- block reduction ----
    #pragma unroll
    for (int off = 32; off > 0; off >>= 1)
        local += __shfl_down(local, off, 64);

    int wave = tid >> 6, lane = tid & 63;
    if (lane == 0) wsum[wave] = local;
    __syncthreads();
    if (tid == 0) {
        double t = (double)wsum[0] + (double)wsum[1] + (double)wsum[2] + (double)wsum[3];
        if (use_partials) {
            int bid = (blockIdx.z * gridDim.y + blockIdx.y) * gridDim.x + blockIdx.x;
            partials[bid] = t;
        } else {
            atomicAdd(sum_out, t);
        }
    }
}

// ---------------- kernel 3: final reduce + mean ----------------
__global__ __launch_bounds__(256) void reduce_kernel(const double* __restrict__ sum,
                                                     const double* __restrict__ partials,
                                                     int use_partials,
                                                     float* __restrict__ out) {
    if (use_partials) {
        double local = 0.0;
        for (int i = threadIdx.x; i < NBLK; i += 256) local += partials[i];
        #pragma unroll
        for (int off = 32; off > 0; off >>= 1)
            local += __shfl_down(local, off, 64);
        __shared__ double ws2[4];
        int wave = threadIdx.x >> 6, lane = threadIdx.x & 63;
        if (lane == 0) ws2[wave] = local;
        __syncthreads();
        if (threadIdx.x == 0)
            out[0] = (float)((ws2[0] + ws2[1] + ws2[2] + ws2[3]) / (double)NOUT);
    } else {
        if (threadIdx.x == 0) out[0] = (float)(sum[0] / (double)NOUT);
    }
}

extern "C" void kernel_launch(void* const* d_in, const int* in_sizes, int n_in,
                              void* d_out, int out_size, void* d_ws, size_t ws_size,
                              hipStream_t stream) {
    const float* img1 = (const float*)d_in[0];
    const float* img2 = (const float*)d_in[1];
    float* out = (float*)d_out;

    // ws layout: [0..7] flags, [8..15] double sum, [16..] per-block partials
    unsigned* flags = (unsigned*)d_ws;
    double* sum = (double*)((char*)d_ws + 8);
    double* partials = (double*)((char*)d_ws + 16);
    int use_partials = (ws_size >= 16 + (size_t)NBLK * sizeof(double)) ? 1 : 0;

    hipMemsetAsync(d_ws, 0, 16, stream);

    // Gaussian taps (float64 math then cast, matching numpy reference)
    GaussW gw;
    {
        double g[WS], s = 0.0;
        for (int i = 0; i < WS; ++i) {
            double x = (double)(i - WS / 2);
            g[i] = exp(-(x * x) / (2.0 * 1.5 * 1.5));
            s += g[i];
        }
        for (int i = 0; i < WS; ++i) gw.g[i] = (float)(g[i] / s);
    }

    int n = in_sizes[0];           // 25,165,824 floats
    flags_kernel<<<2048, 256, 0, stream>>>(img1, flags, n / 4);

    dim3 grid(GX, GY, NPLANES);    // 16 x 16 x 96
    ssim_kernel<<<grid, 256, 0, stream>>>(img1, img2, flags, sum, partials, use_partials, gw);

    reduce_kernel<<<1, 256, 0, stream>>>(sum, partials, use_partials, out);
}